// Round 5
// baseline (685.369 us; speedup 1.0000x reference)
//
#include <hip/hip_runtime.h>
#include <hip/hip_bf16.h>

typedef _Float16 f16;
typedef _Float16 f16x8 __attribute__((ext_vector_type(8)));
typedef float f32x4 __attribute__((ext_vector_type(4)));

#define S_LEN 4096
#define DIM   512
#define NH    8
#define DH    64
#define BATCH 2
#define BHDIM (BATCH*NH)   // 16

// ---------------- RMSNorm: x[8192,512] f32 -> xn f16 ----------------
__global__ __launch_bounds__(256) void rmsnorm_kernel(
    const float* __restrict__ x,
    const float* __restrict__ scale,
    f16* __restrict__ xn) {
  int row = blockIdx.x;
  int tid = threadIdx.x;               // 256 threads, 2 elems each
  const float* xr = x + (size_t)row * DIM;
  float2 v = *(const float2*)(xr + tid*2);
  float ss = v.x*v.x + v.y*v.y;
  #pragma unroll
  for (int off = 32; off > 0; off >>= 1) ss += __shfl_down(ss, off);
  __shared__ float red[4];
  if ((tid & 63) == 0) red[tid >> 6] = ss;
  __syncthreads();
  float tot = red[0] + red[1] + red[2] + red[3];
  float inv = rsqrtf(tot * (1.0f/DIM) + 1e-6f);
  float2 s = *(const float2*)(scale + tid*2);
  xn[(size_t)row*DIM + tid*2+0] = (f16)(v.x*inv*s.x);
  xn[(size_t)row*DIM + tid*2+1] = (f16)(v.y*inv*s.y);
}

// ------------- Transpose+convert weights: W[k][n] f32 -> Wt[n][k] f16 -------------
__global__ void transpose_kernel(const float* __restrict__ Wq,
                                 const float* __restrict__ Wk,
                                 const float* __restrict__ Wv,
                                 const float* __restrict__ Wo,
                                 f16* __restrict__ wt_qkv, f16* __restrict__ wo_t) {
  __shared__ f16 tile[32][33];
  int mat = blockIdx.z;
  const float* src = (mat == 0) ? Wq : (mat == 1) ? Wk : (mat == 2) ? Wv : Wo;
  f16* dst = (mat < 3) ? (wt_qkv + (size_t)mat*DIM*DIM) : wo_t;
  int k0 = blockIdx.y * 32, n0 = blockIdx.x * 32;
  int tx = threadIdx.x, ty = threadIdx.y;  // (32, 8)
  #pragma unroll
  for (int i = 0; i < 32; i += 8)
    tile[ty+i][tx] = (f16)src[(size_t)(k0+ty+i)*DIM + n0+tx];
  __syncthreads();
  #pragma unroll
  for (int i = 0; i < 32; i += 8)
    dst[(size_t)(n0+ty+i)*DIM + k0+tx] = tile[tx][ty+i];
}

// ------------- QKV GEMM: xn[8192,512] @ W -> q,k in [bh][s][64], v transposed [bh][64][s] -------------
__global__ __launch_bounds__(256) void qkv_gemm_kernel(
    const f16* __restrict__ xn, const f16* __restrict__ wt,
    f16* __restrict__ qbuf, f16* __restrict__ kbuf, f16* __restrict__ vt) {
  int m0 = blockIdx.x * 64;
  int n0 = blockIdx.y * 64;                 // 0..1535
  int wave = threadIdx.x >> 6;
  int lane = threadIdx.x & 63;
  int l16 = lane & 15, quad = lane >> 4;

  f32x4 acc[4] = {};
  const f16* arow = xn + (size_t)(m0 + wave*16 + l16)*DIM + quad*8;
  #pragma unroll 4
  for (int k0 = 0; k0 < DIM; k0 += 32) {
    f16x8 a = *(const f16x8*)(arow + k0);
    #pragma unroll
    for (int nt = 0; nt < 4; nt++) {
      f16x8 b = *(const f16x8*)(wt + (size_t)(n0 + nt*16 + l16)*DIM + k0 + quad*8);
      acc[nt] = __builtin_amdgcn_mfma_f32_16x16x32_f16(a, b, acc[nt], 0, 0, 0);
    }
  }
  int which = n0 / 512;            // 0=q 1=k 2=v (uniform per block)
  int head  = (n0 % 512) / 64;     // uniform per block
  int m_base = m0 + wave*16 + quad*4;
  #pragma unroll
  for (int nt = 0; nt < 4; nt++) {
    int d = nt*16 + l16;
    #pragma unroll
    for (int r = 0; r < 4; r++) {
      int m = m_base + r;
      int b = m >> 12;             // /4096
      int t = m & 4095;
      int bh = b*NH + head;
      f16 val = (f16)acc[nt][r];
      if (which == 0)      qbuf[((size_t)bh*S_LEN + t)*DH + d] = val;
      else if (which == 1) kbuf[((size_t)bh*S_LEN + t)*DH + d] = val;
      else                 vt[((size_t)bh*DH + d)*S_LEN + t] = val;
    }
  }
}

// ------------- RoPE in-place on q,k (f32 trig) -------------
__global__ __launch_bounds__(256) void rope_kernel(f16* __restrict__ qbuf,
                                                   f16* __restrict__ kbuf) {
  int gid = blockIdx.x * 256 + threadIdx.x;
  int item = gid & 63;             // 0..31 q pair, 32..63 k pair
  int row = gid >> 6;              // 0 .. 16*4096-1
  int t = row & 4095;
  int bh = row >> 12;
  int j = item & 31;
  f16* buf = (item & 32) ? kbuf : qbuf;
  size_t base = ((size_t)bh*S_LEN + t)*DH;
  // theta = 1e6^(-j/32) computed as exp2(-j*log2(1e6)/32)
  float theta = exp2f(-(float)j * (19.931568569324174f / 32.0f));
  float ang = (float)t * theta;
  float sv, cv;
  sincosf(ang, &sv, &cv);
  float x1 = (float)buf[base + j];
  float x2 = (float)buf[base + j + 32];
  buf[base + j]      = (f16)(x1*cv - x2*sv);
  buf[base + j + 32] = (f16)(x1*sv + x2*cv);
}

// ------------- Flash attention (causal), 64 q-rows/block, 4 waves x 16 rows -------------
__global__ __launch_bounds__(256) void attn_kernel(
    const f16* __restrict__ qbuf, const f16* __restrict__ kbuf,
    const f16* __restrict__ vt, f16* __restrict__ ao) {
  int qt = blockIdx.x;             // 0..63
  int bh = blockIdx.y;             // 0..15
  int wave = threadIdx.x >> 6;
  int lane = threadIdx.x & 63;
  int l16 = lane & 15, quad = lane >> 4;

  const f16* Q = qbuf + (size_t)bh*S_LEN*DH;
  const f16* K = kbuf + (size_t)bh*S_LEN*DH;
  const f16* V = vt   + (size_t)bh*DH*S_LEN;

  // Q A-fragments (row = m, k = dh), loaded once
  int m_row = qt*64 + wave*16 + l16;
  f16x8 qa0 = *(const f16x8*)(Q + (size_t)m_row*DH + quad*8);
  f16x8 qa1 = *(const f16x8*)(Q + (size_t)m_row*DH + 32 + quad*8);

  f32x4 o[4] = {};                 // O tile 16x64 in C-layout (4 n-frags)
  float m_i[4], l_i[4];
  #pragma unroll
  for (int r = 0; r < 4; r++) { m_i[r] = -1e30f; l_i[r] = 0.f; }

  __shared__ __align__(16) f16 pls[4][16][80];   // wave-private P staging

  int q_row_base = qt*64 + wave*16 + quad*4;

  int niter = qt + 1;
  for (int it = 0; it < niter; ++it) {
    int kv0 = it * 64;
    // S = Q K^T  (4 n-tiles of 16 keys)
    f32x4 s[4];
    #pragma unroll
    for (int nt = 0; nt < 4; nt++) {
      const f16* krow = K + (size_t)(kv0 + nt*16 + l16)*DH + quad*8;
      f16x8 kb0 = *(const f16x8*)(krow);
      f16x8 kb1 = *(const f16x8*)(krow + 32);
      f32x4 z = {};
      z = __builtin_amdgcn_mfma_f32_16x16x32_f16(qa0, kb0, z, 0, 0, 0);
      s[nt] = __builtin_amdgcn_mfma_f32_16x16x32_f16(qa1, kb1, z, 0, 0, 0);
    }
    // scale + causal mask + row max
    float rmax[4];
    #pragma unroll
    for (int r = 0; r < 4; r++) rmax[r] = -1e30f;
    #pragma unroll
    for (int nt = 0; nt < 4; nt++) {
      int key = kv0 + nt*16 + l16;
      #pragma unroll
      for (int r = 0; r < 4; r++) {
        float v = s[nt][r] * 0.125f;
        if (key > q_row_base + r) v = -1e30f;
        s[nt][r] = v;
        rmax[r] = fmaxf(rmax[r], v);
      }
    }
    #pragma unroll
    for (int r = 0; r < 4; r++) {
      float v = rmax[r];
      v = fmaxf(v, __shfl_xor(v, 1));
      v = fmaxf(v, __shfl_xor(v, 2));
      v = fmaxf(v, __shfl_xor(v, 4));
      v = fmaxf(v, __shfl_xor(v, 8));
      rmax[r] = v;
    }
    float alpha[4], rsum[4];
    #pragma unroll
    for (int r = 0; r < 4; r++) {
      float mnew = fmaxf(m_i[r], rmax[r]);
      alpha[r] = __expf(m_i[r] - mnew);
      m_i[r] = mnew;
      rsum[r] = 0.f;
    }
    #pragma unroll
    for (int nt = 0; nt < 4; nt++) {
      #pragma unroll
      for (int r = 0; r < 4; r++) {
        float p = __expf(s[nt][r] - m_i[r]);
        s[nt][r] = p;
        rsum[r] += p;
      }
    }
    #pragma unroll
    for (int r = 0; r < 4; r++) {
      float v = rsum[r];
      v += __shfl_xor(v, 1);
      v += __shfl_xor(v, 2);
      v += __shfl_xor(v, 4);
      v += __shfl_xor(v, 8);
      l_i[r] = l_i[r]*alpha[r] + v;
    }
    // P (C-layout) -> LDS -> A-layout; rescale O by alpha
    #pragma unroll
    for (int nt = 0; nt < 4; nt++) {
      #pragma unroll
      for (int r = 0; r < 4; r++) {
        pls[wave][quad*4 + r][nt*16 + l16] = (f16)s[nt][r];
        o[nt][r] *= alpha[r];
      }
    }
    f16x8 pa0 = *(const f16x8*)(&pls[wave][l16][quad*8]);
    f16x8 pa1 = *(const f16x8*)(&pls[wave][l16][32 + quad*8]);
    // O += P V   (V^T layout: contiguous in kv for fixed dh)
    #pragma unroll
    for (int nt = 0; nt < 4; nt++) {
      const f16* vrow = V + (size_t)(nt*16 + l16)*S_LEN + kv0 + quad*8;
      f16x8 vb0 = *(const f16x8*)(vrow);
      f16x8 vb1 = *(const f16x8*)(vrow + 32);
      o[nt] = __builtin_amdgcn_mfma_f32_16x16x32_f16(pa0, vb0, o[nt], 0, 0, 0);
      o[nt] = __builtin_amdgcn_mfma_f32_16x16x32_f16(pa1, vb1, o[nt], 0, 0, 0);
    }
  }
  // epilogue: O/l -> ao[b*4096+t][h*64+d]
  int b = bh >> 3, h = bh & 7;
  #pragma unroll
  for (int r = 0; r < 4; r++) {
    float invl = 1.0f / l_i[r];
    int t = qt*64 + wave*16 + quad*4 + r;
    size_t rowoff = ((size_t)(b*S_LEN + t))*DIM + h*DH;
    #pragma unroll
    for (int nt = 0; nt < 4; nt++)
      ao[rowoff + nt*16 + l16] = (f16)(o[nt][r]*invl);
  }
}

// ------------- Output GEMM: ao[8192,512] @ Wo -> out f32 -------------
__global__ __launch_bounds__(256) void out_gemm_kernel(
    const f16* __restrict__ ao, const f16* __restrict__ wot,
    float* __restrict__ out) {
  int m0 = blockIdx.x * 64, n0 = blockIdx.y * 64;
  int wave = threadIdx.x >> 6, lane = threadIdx.x & 63;
  int l16 = lane & 15, quad = lane >> 4;
  f32x4 acc[4] = {};
  const f16* arow = ao + (size_t)(m0 + wave*16 + l16)*DIM + quad*8;
  #pragma unroll 4
  for (int k0 = 0; k0 < DIM; k0 += 32) {
    f16x8 a = *(const f16x8*)(arow + k0);
    #pragma unroll
    for (int nt = 0; nt < 4; nt++) {
      f16x8 b = *(const f16x8*)(wot + (size_t)(n0 + nt*16 + l16)*DIM + k0 + quad*8);
      acc[nt] = __builtin_amdgcn_mfma_f32_16x16x32_f16(a, b, acc[nt], 0, 0, 0);
    }
  }
  int m_base = m0 + wave*16 + quad*4;
  #pragma unroll
  for (int nt = 0; nt < 4; nt++)
    #pragma unroll
    for (int r = 0; r < 4; r++)
      out[(size_t)(m_base + r)*DIM + n0 + nt*16 + l16] = acc[nt][r];   // f32 store
}

extern "C" void kernel_launch(void* const* d_in, const int* in_sizes, int n_in,
                              void* d_out, int out_size, void* d_ws, size_t ws_size,
                              hipStream_t stream) {
  const float* x     = (const float*)d_in[0];
  const float* scale = (const float*)d_in[1];
  const float* Wq    = (const float*)d_in[2];
  const float* Wk    = (const float*)d_in[3];
  const float* Wv    = (const float*)d_in[4];
  const float* Wo    = (const float*)d_in[5];
  float* out = (float*)d_out;    // output is float32 (threshold = 2% * max|ref| exactly)

  const size_t ROWS = (size_t)BATCH * S_LEN;   // 8192
  char* ws = (char*)d_ws;
  f16* xn     = (f16*)ws;  ws += ROWS * DIM * sizeof(f16);            // 8 MB (reused as ao)
  f16* wt_qkv = (f16*)ws;  ws += (size_t)3 * DIM * DIM * sizeof(f16); // 1.5 MB
  f16* wo_t   = (f16*)ws;  ws += (size_t)DIM * DIM * sizeof(f16);     // 0.5 MB
  f16* qb     = (f16*)ws;  ws += (size_t)BHDIM * S_LEN * DH * sizeof(f16); // 8 MB
  f16* kb     = (f16*)ws;  ws += (size_t)BHDIM * S_LEN * DH * sizeof(f16); // 8 MB
  f16* vt     = (f16*)ws;  ws += (size_t)BHDIM * S_LEN * DH * sizeof(f16); // 8 MB
  f16* ao     = xn;  // overlay: xn dead after qkv_gemm, ao written by attn afterwards

  size_t need = (size_t)(ws - (char*)d_ws);
  if (ws_size < need) return;   // insufficient workspace -> loud failure (out stays 0)

  rmsnorm_kernel  <<<ROWS, 256, 0, stream>>>(x, scale, xn);
  transpose_kernel<<<dim3(16,16,4), dim3(32,8), 0, stream>>>(Wq, Wk, Wv, Wo, wt_qkv, wo_t);
  qkv_gemm_kernel <<<dim3(128,24), 256, 0, stream>>>(xn, wt_qkv, qb, kb, vt);
  rope_kernel     <<<(BHDIM*S_LEN*64)/256, 256, 0, stream>>>(qb, kb);
  attn_kernel     <<<dim3(64,16), 256, 0, stream>>>(qb, kb, vt, ao);
  out_gemm_kernel <<<dim3(128,8), 256, 0, stream>>>(ao, wo_t, out);
}

// Round 6
// 453.188 us; speedup vs baseline: 1.5123x; 1.5123x over previous
//
#include <hip/hip_runtime.h>
#include <hip/hip_bf16.h>

typedef _Float16 f16;
typedef _Float16 f16x8 __attribute__((ext_vector_type(8)));
typedef float f32x4 __attribute__((ext_vector_type(4)));

#define S_LEN 4096
#define DIM   512
#define NH    8
#define DH    64
#define BATCH 2
#define BHDIM (BATCH*NH)   // 16

// ---------------- RMSNorm: x[8192,512] f32 -> xn f16 ----------------
__global__ __launch_bounds__(256) void rmsnorm_kernel(
    const float* __restrict__ x,
    const float* __restrict__ scale,
    f16* __restrict__ xn) {
  int row = blockIdx.x;
  int tid = threadIdx.x;               // 256 threads, 2 elems each
  const float* xr = x + (size_t)row * DIM;
  float2 v = *(const float2*)(xr + tid*2);
  float ss = v.x*v.x + v.y*v.y;
  #pragma unroll
  for (int off = 32; off > 0; off >>= 1) ss += __shfl_down(ss, off);
  __shared__ float red[4];
  if ((tid & 63) == 0) red[tid >> 6] = ss;
  __syncthreads();
  float tot = red[0] + red[1] + red[2] + red[3];
  float inv = rsqrtf(tot * (1.0f/DIM) + 1e-6f);
  float2 s = *(const float2*)(scale + tid*2);
  xn[(size_t)row*DIM + tid*2+0] = (f16)(v.x*inv*s.x);
  xn[(size_t)row*DIM + tid*2+1] = (f16)(v.y*inv*s.y);
}

// ------------- Transpose+convert weights: W[k][n] f32 -> Wt[n][k] f16 -------------
__global__ void transpose_kernel(const float* __restrict__ Wq,
                                 const float* __restrict__ Wk,
                                 const float* __restrict__ Wv,
                                 const float* __restrict__ Wo,
                                 f16* __restrict__ wt_qkv, f16* __restrict__ wo_t) {
  __shared__ f16 tile[32][33];
  int mat = blockIdx.z;
  const float* src = (mat == 0) ? Wq : (mat == 1) ? Wk : (mat == 2) ? Wv : Wo;
  f16* dst = (mat < 3) ? (wt_qkv + (size_t)mat*DIM*DIM) : wo_t;
  int k0 = blockIdx.y * 32, n0 = blockIdx.x * 32;
  int tx = threadIdx.x, ty = threadIdx.y;  // (32, 8)
  #pragma unroll
  for (int i = 0; i < 32; i += 8)
    tile[ty+i][tx] = (f16)src[(size_t)(k0+ty+i)*DIM + n0+tx];
  __syncthreads();
  #pragma unroll
  for (int i = 0; i < 32; i += 8)
    dst[(size_t)(n0+ty+i)*DIM + k0+tx] = tile[tx][ty+i];
}

// ------------- QKV GEMM + fused RoPE: xn @ W -> q,k (roped) [bh][s][64], v transposed [bh][64][s] -------------
__global__ __launch_bounds__(256) void qkv_gemm_kernel(
    const f16* __restrict__ xn, const f16* __restrict__ wt,
    f16* __restrict__ qbuf, f16* __restrict__ kbuf, f16* __restrict__ vt) {
  int m0 = blockIdx.x * 64;
  int n0 = blockIdx.y * 64;                 // 0..1535
  int wave = threadIdx.x >> 6;
  int lane = threadIdx.x & 63;
  int l16 = lane & 15, quad = lane >> 4;

  f32x4 acc[4] = {};
  const f16* arow = xn + (size_t)(m0 + wave*16 + l16)*DIM + quad*8;
  #pragma unroll 4
  for (int k0 = 0; k0 < DIM; k0 += 32) {
    f16x8 a = *(const f16x8*)(arow + k0);
    #pragma unroll
    for (int nt = 0; nt < 4; nt++) {
      f16x8 b = *(const f16x8*)(wt + (size_t)(n0 + nt*16 + l16)*DIM + k0 + quad*8);
      acc[nt] = __builtin_amdgcn_mfma_f32_16x16x32_f16(a, b, acc[nt], 0, 0, 0);
    }
  }
  int which = n0 / 512;            // 0=q 1=k 2=v (uniform per block)
  int head  = (n0 % 512) / 64;     // uniform per block
  int m_base = m0 + wave*16 + quad*4;

  // Fused RoPE for q and k: pairs (d, d+32) = (acc[nt], acc[nt+2]), nt=0,1
  if (which <= 1) {
    #pragma unroll
    for (int nt = 0; nt < 2; nt++) {
      float d = (float)(nt*16 + l16);                 // 0..31
      float theta = exp2f(-d * (19.931568569324174f / 32.0f));
      #pragma unroll
      for (int r = 0; r < 4; r++) {
        int t = (m_base + r) & 4095;
        float sv, cv;
        sincosf((float)t * theta, &sv, &cv);
        float x1 = acc[nt][r], x2 = acc[nt+2][r];
        acc[nt][r]   = x1*cv - x2*sv;
        acc[nt+2][r] = x1*sv + x2*cv;
      }
    }
  }

  #pragma unroll
  for (int nt = 0; nt < 4; nt++) {
    int d = nt*16 + l16;
    #pragma unroll
    for (int r = 0; r < 4; r++) {
      int m = m_base + r;
      int b = m >> 12;             // /4096
      int t = m & 4095;
      int bh = b*NH + head;
      f16 val = (f16)acc[nt][r];
      if (which == 0)      qbuf[((size_t)bh*S_LEN + t)*DH + d] = val;
      else if (which == 1) kbuf[((size_t)bh*S_LEN + t)*DH + d] = val;
      else                 vt[((size_t)bh*DH + d)*S_LEN + t] = val;
    }
  }
}

// ------------- Flash attention (causal), 128 q-rows/block, LDS-staged double-buffered KV -------------
// 4 waves; wave w owns q rows [qt*128 + w*32, +32) as 2 m-frags.
__global__ __launch_bounds__(256) void attn_kernel(
    const f16* __restrict__ qbuf, const f16* __restrict__ kbuf,
    const f16* __restrict__ vtb, f16* __restrict__ ao) {
  int qtb = (int)(gridDim.x - 1) - (int)blockIdx.x;   // reversed: heavy blocks dispatch first
  int bh = blockIdx.y;             // 0..15
  int tid = threadIdx.x;
  int wave = tid >> 6;
  int lane = tid & 63;
  int l16 = lane & 15, quad = lane >> 4;

  const f16* Q = qbuf + (size_t)bh*S_LEN*DH;
  const f16* K = kbuf + (size_t)bh*S_LEN*DH;
  const f16* V = vtb  + (size_t)bh*DH*S_LEN;   // [dh][s]

  int rw = qtb*128 + wave*32;      // wave's first q row

  // Q A-fragments, loaded once: qa[mf][k-half]
  f16x8 qa[2][2];
  #pragma unroll
  for (int mf = 0; mf < 2; mf++) {
    const f16* qrow = Q + (size_t)(rw + mf*16 + l16)*DH + quad*8;
    qa[mf][0] = *(const f16x8*)(qrow);
    qa[mf][1] = *(const f16x8*)(qrow + 32);
  }

  f32x4 o[2][4] = {};
  float m_i[2][4], l_i[2][4];
  #pragma unroll
  for (int mf = 0; mf < 2; mf++)
    #pragma unroll
    for (int r = 0; r < 4; r++) { m_i[mf][r] = -1e30f; l_i[mf][r] = 0.f; }

  // LDS: stride 72 f16 (144B = 36 words) -> 2-way bank pattern on b128 frag reads (free)
  __shared__ __align__(16) f16 kt[2][64][72];   // [buf][kv][dh]
  __shared__ __align__(16) f16 vs[2][64][72];   // [buf][dh][kv]
  __shared__ __align__(16) f16 pls[4][16][72];  // per-wave P staging

  int ntiles = 2*qtb + 2;

  // staging map: thread handles 16B chunks {tid, tid+256} of each 8KB tile
  int row0 = tid >> 3,        c0 = (tid & 7) * 8;
  int row1 = (tid+256) >> 3,  c1 = ((tid+256) & 7) * 8;

  // prologue: stage tile 0 into buf 0
  {
    f16x8 a0 = *(const f16x8*)(K + (size_t)row0*DH + c0);
    f16x8 a1 = *(const f16x8*)(K + (size_t)row1*DH + c1);
    f16x8 b0 = *(const f16x8*)(V + (size_t)row0*S_LEN + c0);
    f16x8 b1 = *(const f16x8*)(V + (size_t)row1*S_LEN + c1);
    *(f16x8*)&kt[0][row0][c0] = a0;
    *(f16x8*)&kt[0][row1][c1] = a1;
    *(f16x8*)&vs[0][row0][c0] = b0;
    *(f16x8*)&vs[0][row1][c1] = b1;
  }
  __syncthreads();

  int buf = 0;
  for (int it = 0; it < ntiles; ++it) {
    int kv0 = it * 64;
    bool have_next = (it + 1 < ntiles);
    f16x8 pk0, pk1, pv0, pv1;
    if (have_next) {               // prefetch next tile into regs (overlaps compute)
      int kvn = kv0 + 64;
      pk0 = *(const f16x8*)(K + (size_t)(kvn + row0)*DH + c0);
      pk1 = *(const f16x8*)(K + (size_t)(kvn + row1)*DH + c1);
      pv0 = *(const f16x8*)(V + (size_t)row0*S_LEN + kvn + c0);
      pv1 = *(const f16x8*)(V + (size_t)row1*S_LEN + kvn + c1);
    }

    if (kv0 <= rw + 31) {          // wave-uniform: tile intersects this wave's causal range
      // ---- S = Q K^T for both m-frags (K frags shared) ----
      f32x4 s[2][4];
      #pragma unroll
      for (int nt = 0; nt < 4; nt++) {
        f16x8 kf0 = *(const f16x8*)&kt[buf][nt*16 + l16][quad*8];
        f16x8 kf1 = *(const f16x8*)&kt[buf][nt*16 + l16][32 + quad*8];
        f32x4 z0 = {}, z1 = {};
        z0 = __builtin_amdgcn_mfma_f32_16x16x32_f16(qa[0][0], kf0, z0, 0, 0, 0);
        z1 = __builtin_amdgcn_mfma_f32_16x16x32_f16(qa[1][0], kf0, z1, 0, 0, 0);
        s[0][nt] = __builtin_amdgcn_mfma_f32_16x16x32_f16(qa[0][1], kf1, z0, 0, 0, 0);
        s[1][nt] = __builtin_amdgcn_mfma_f32_16x16x32_f16(qa[1][1], kf1, z1, 0, 0, 0);
      }
      // ---- softmax + PV per m-frag ----
      #pragma unroll
      for (int mf = 0; mf < 2; mf++) {
        int qbase = rw + mf*16;
        float rmax[4];
        #pragma unroll
        for (int r = 0; r < 4; r++) rmax[r] = -1e30f;
        if (kv0 + 63 > qbase) {    // diagonal tile: mask needed (wave-uniform branch)
          #pragma unroll
          for (int nt = 0; nt < 4; nt++) {
            int key = kv0 + nt*16 + l16;
            #pragma unroll
            for (int r = 0; r < 4; r++) {
              float v = s[mf][nt][r] * 0.125f;
              if (key > qbase + quad*4 + r) v = -1e30f;
              s[mf][nt][r] = v;
              rmax[r] = fmaxf(rmax[r], v);
            }
          }
        } else {
          #pragma unroll
          for (int nt = 0; nt < 4; nt++)
            #pragma unroll
            for (int r = 0; r < 4; r++) {
              float v = s[mf][nt][r] * 0.125f;
              s[mf][nt][r] = v;
              rmax[r] = fmaxf(rmax[r], v);
            }
        }
        #pragma unroll
        for (int r = 0; r < 4; r++) {
          float v = rmax[r];
          v = fmaxf(v, __shfl_xor(v, 1));
          v = fmaxf(v, __shfl_xor(v, 2));
          v = fmaxf(v, __shfl_xor(v, 4));
          v = fmaxf(v, __shfl_xor(v, 8));
          rmax[r] = v;
        }
        float alpha[4], rsum[4];
        #pragma unroll
        for (int r = 0; r < 4; r++) {
          float mnew = fmaxf(m_i[mf][r], rmax[r]);
          alpha[r] = __expf(m_i[mf][r] - mnew);
          m_i[mf][r] = mnew;
          rsum[r] = 0.f;
        }
        #pragma unroll
        for (int nt = 0; nt < 4; nt++)
          #pragma unroll
          for (int r = 0; r < 4; r++) {
            float p = __expf(s[mf][nt][r] - m_i[mf][r]);
            s[mf][nt][r] = p;
            rsum[r] += p;
          }
        #pragma unroll
        for (int r = 0; r < 4; r++) {
          float v = rsum[r];
          v += __shfl_xor(v, 1);
          v += __shfl_xor(v, 2);
          v += __shfl_xor(v, 4);
          v += __shfl_xor(v, 8);
          l_i[mf][r] = l_i[mf][r]*alpha[r] + v;
        }
        // P (C-layout) -> LDS -> A-layout; rescale O
        #pragma unroll
        for (int nt = 0; nt < 4; nt++)
          #pragma unroll
          for (int r = 0; r < 4; r++) {
            pls[wave][quad*4 + r][nt*16 + l16] = (f16)s[mf][nt][r];
            o[mf][nt][r] *= alpha[r];
          }
        f16x8 pa0 = *(const f16x8*)(&pls[wave][l16][quad*8]);
        f16x8 pa1 = *(const f16x8*)(&pls[wave][l16][32 + quad*8]);
        #pragma unroll
        for (int nt = 0; nt < 4; nt++) {
          f16x8 vf0 = *(const f16x8*)&vs[buf][nt*16 + l16][quad*8];
          f16x8 vf1 = *(const f16x8*)&vs[buf][nt*16 + l16][32 + quad*8];
          o[mf][nt] = __builtin_amdgcn_mfma_f32_16x16x32_f16(pa0, vf0, o[mf][nt], 0, 0, 0);
          o[mf][nt] = __builtin_amdgcn_mfma_f32_16x16x32_f16(pa1, vf1, o[mf][nt], 0, 0, 0);
        }
      }
    }

    if (have_next) {               // commit prefetched tile to the other buffer
      int nb = buf ^ 1;
      *(f16x8*)&kt[nb][row0][c0] = pk0;
      *(f16x8*)&kt[nb][row1][c1] = pk1;
      *(f16x8*)&vs[nb][row0][c0] = pv0;
      *(f16x8*)&vs[nb][row1][c1] = pv1;
    }
    __syncthreads();
    buf ^= 1;
  }

  // epilogue: O/l -> ao[b*4096+t][h*64+d]
  int b = bh >> 3, h = bh & 7;
  #pragma unroll
  for (int mf = 0; mf < 2; mf++)
    #pragma unroll
    for (int r = 0; r < 4; r++) {
      float invl = 1.0f / l_i[mf][r];
      int t = rw + mf*16 + quad*4 + r;
      size_t rowoff = ((size_t)(b*S_LEN + t))*DIM + h*DH;
      #pragma unroll
      for (int nt = 0; nt < 4; nt++)
        ao[rowoff + nt*16 + l16] = (f16)(o[mf][nt][r]*invl);
    }
}

// ------------- Output GEMM: ao[8192,512] @ Wo -> out f32 -------------
__global__ __launch_bounds__(256) void out_gemm_kernel(
    const f16* __restrict__ ao, const f16* __restrict__ wot,
    float* __restrict__ out) {
  int m0 = blockIdx.x * 64, n0 = blockIdx.y * 64;
  int wave = threadIdx.x >> 6, lane = threadIdx.x & 63;
  int l16 = lane & 15, quad = lane >> 4;
  f32x4 acc[4] = {};
  const f16* arow = ao + (size_t)(m0 + wave*16 + l16)*DIM + quad*8;
  #pragma unroll 4
  for (int k0 = 0; k0 < DIM; k0 += 32) {
    f16x8 a = *(const f16x8*)(arow + k0);
    #pragma unroll
    for (int nt = 0; nt < 4; nt++) {
      f16x8 b = *(const f16x8*)(wot + (size_t)(n0 + nt*16 + l16)*DIM + k0 + quad*8);
      acc[nt] = __builtin_amdgcn_mfma_f32_16x16x32_f16(a, b, acc[nt], 0, 0, 0);
    }
  }
  int m_base = m0 + wave*16 + quad*4;
  #pragma unroll
  for (int nt = 0; nt < 4; nt++)
    #pragma unroll
    for (int r = 0; r < 4; r++)
      out[(size_t)(m_base + r)*DIM + n0 + nt*16 + l16] = acc[nt][r];   // f32 store
}

extern "C" void kernel_launch(void* const* d_in, const int* in_sizes, int n_in,
                              void* d_out, int out_size, void* d_ws, size_t ws_size,
                              hipStream_t stream) {
  const float* x     = (const float*)d_in[0];
  const float* scale = (const float*)d_in[1];
  const float* Wq    = (const float*)d_in[2];
  const float* Wk    = (const float*)d_in[3];
  const float* Wv    = (const float*)d_in[4];
  const float* Wo    = (const float*)d_in[5];
  float* out = (float*)d_out;

  const size_t ROWS = (size_t)BATCH * S_LEN;   // 8192
  char* ws = (char*)d_ws;
  f16* xn     = (f16*)ws;  ws += ROWS * DIM * sizeof(f16);            // 8 MB (reused as ao)
  f16* wt_qkv = (f16*)ws;  ws += (size_t)3 * DIM * DIM * sizeof(f16); // 1.5 MB
  f16* wo_t   = (f16*)ws;  ws += (size_t)DIM * DIM * sizeof(f16);     // 0.5 MB
  f16* qb     = (f16*)ws;  ws += (size_t)BHDIM * S_LEN * DH * sizeof(f16); // 8 MB
  f16* kb     = (f16*)ws;  ws += (size_t)BHDIM * S_LEN * DH * sizeof(f16); // 8 MB
  f16* vt     = (f16*)ws;  ws += (size_t)BHDIM * S_LEN * DH * sizeof(f16); // 8 MB
  f16* ao     = xn;  // overlay: xn dead after qkv_gemm, ao written by attn afterwards

  size_t need = (size_t)(ws - (char*)d_ws);
  if (ws_size < need) return;   // insufficient workspace -> loud failure (out stays 0)

  rmsnorm_kernel  <<<ROWS, 256, 0, stream>>>(x, scale, xn);
  transpose_kernel<<<dim3(16,16,4), dim3(32,8), 0, stream>>>(Wq, Wk, Wv, Wo, wt_qkv, wo_t);
  qkv_gemm_kernel <<<dim3(128,24), 256, 0, stream>>>(xn, wt_qkv, qb, kb, vt);
  attn_kernel     <<<dim3(32,16), 256, 0, stream>>>(qb, kb, vt, ao);
  out_gemm_kernel <<<dim3(128,8), 256, 0, stream>>>(ao, wo_t, out);
}

// Round 7
// 303.256 us; speedup vs baseline: 2.2600x; 1.4944x over previous
//
#include <hip/hip_runtime.h>
#include <hip/hip_bf16.h>

typedef _Float16 f16;
typedef _Float16 f16x4 __attribute__((ext_vector_type(4)));
typedef _Float16 f16x8 __attribute__((ext_vector_type(8)));
typedef float f32x4 __attribute__((ext_vector_type(4)));

#define S_LEN 4096
#define DIM   512
#define NH    8
#define DH    64
#define BATCH 2
#define BHDIM (BATCH*NH)   // 16

// Q pre-scale: 1/sqrt(64) * log2(e)  (softmax done in exp2 domain)
#define QSCALE 0.18033688011112042f

__device__ __forceinline__ void gld16(const f16* g, f16* l) {
#if __has_builtin(__builtin_amdgcn_global_load_lds)
  __builtin_amdgcn_global_load_lds((const __attribute__((address_space(1))) void*)g,
                                   (__attribute__((address_space(3))) void*)l, 16, 0, 0);
#else
  *(f16x8*)l = *(const f16x8*)g;
#endif
}

// ---------------- RMSNorm: x[8192,512] f32 -> xn f16 ----------------
__global__ __launch_bounds__(256) void rmsnorm_kernel(
    const float* __restrict__ x, const float* __restrict__ scale,
    f16* __restrict__ xn) {
  int row = blockIdx.x;
  int tid = threadIdx.x;
  const float* xr = x + (size_t)row * DIM;
  float2 v = *(const float2*)(xr + tid*2);
  float ss = v.x*v.x + v.y*v.y;
  #pragma unroll
  for (int off = 32; off > 0; off >>= 1) ss += __shfl_down(ss, off);
  __shared__ float red[4];
  if ((tid & 63) == 0) red[tid >> 6] = ss;
  __syncthreads();
  float tot = red[0] + red[1] + red[2] + red[3];
  float inv = rsqrtf(tot * (1.0f/DIM) + 1e-6f);
  float2 s = *(const float2*)(scale + tid*2);
  xn[(size_t)row*DIM + tid*2+0] = (f16)(v.x*inv*s.x);
  xn[(size_t)row*DIM + tid*2+1] = (f16)(v.y*inv*s.y);
}

// ------------- Transpose+convert weights: W[k][n] f32 -> Wt[n][k] f16 -------------
__global__ void transpose_kernel(const float* __restrict__ Wq,
                                 const float* __restrict__ Wk,
                                 const float* __restrict__ Wv,
                                 const float* __restrict__ Wo,
                                 f16* __restrict__ wt_qkv, f16* __restrict__ wo_t) {
  __shared__ f16 tile[32][33];
  int mat = blockIdx.z;
  const float* src = (mat == 0) ? Wq : (mat == 1) ? Wk : (mat == 2) ? Wv : Wo;
  f16* dst = (mat < 3) ? (wt_qkv + (size_t)mat*DIM*DIM) : wo_t;
  int k0 = blockIdx.y * 32, n0 = blockIdx.x * 32;
  int tx = threadIdx.x, ty = threadIdx.y;  // (32, 8)
  #pragma unroll
  for (int i = 0; i < 32; i += 8)
    tile[ty+i][tx] = (f16)src[(size_t)(k0+ty+i)*DIM + n0+tx];
  __syncthreads();
  #pragma unroll
  for (int i = 0; i < 32; i += 8)
    dst[(size_t)(n0+ty+i)*DIM + k0+tx] = tile[tx][ty+i];
}

// ------------- RoPE cos/sin tables: [4096][32] f32 -------------
__global__ __launch_bounds__(256) void rope_table_kernel(float* __restrict__ ctab,
                                                         float* __restrict__ stab) {
  int idx = blockIdx.x*256 + threadIdx.x;   // 0..131071
  int t = idx >> 5, d = idx & 31;
  float theta = exp2f(-(float)d * (19.931568569324174f / 32.0f));
  float sv, cv;
  sincosf((float)t * theta, &sv, &cv);
  ctab[idx] = cv; stab[idx] = sv;
}

// ------------- m97-style 128x128 GEMM core: C = A[M,512] * Bt[N,512]^T -------------
// BK=64, global_load_lds w=16, source-chunk XOR swizzle -> conflict-free b128 frag reads.
__device__ __forceinline__ void gemm128_acc(
    const f16* __restrict__ A, const f16* __restrict__ Bt,
    int m0, int n0, f16* As, f16* Bs, f32x4 (&acc)[4][4]) {
  const int tid = threadIdx.x;
  const int wave = tid >> 6, lane = tid & 63;
  const int l16 = lane & 15, quad = lane >> 4;
  const int mrow = (wave & 1) * 64, ncol = (wave >> 1) * 64;
  const int srow = tid >> 3;                    // 0..31
  const int gc = (tid & 7) ^ ((tid >> 3) & 7);  // swizzled source chunk

  for (int k0 = 0; k0 < DIM; k0 += 64) {
    if (k0) __syncthreads();
    #pragma unroll
    for (int i = 0; i < 4; i++) {
      gld16(A  + (size_t)(m0 + i*32 + srow)*DIM + k0 + gc*8, As + i*2048 + tid*8);
      gld16(Bt + (size_t)(n0 + i*32 + srow)*DIM + k0 + gc*8, Bs + i*2048 + tid*8);
    }
    __syncthreads();
    #pragma unroll
    for (int kc = 0; kc < 2; kc++) {
      f16x8 a[4], b[4];
      #pragma unroll
      for (int mt = 0; mt < 4; mt++) {
        int row = mrow + mt*16 + l16;
        a[mt] = *(const f16x8*)(As + row*64 + (((quad + 4*kc) ^ (l16 & 7)) * 8));
      }
      #pragma unroll
      for (int nt = 0; nt < 4; nt++) {
        int row = ncol + nt*16 + l16;
        b[nt] = *(const f16x8*)(Bs + row*64 + (((quad + 4*kc) ^ (l16 & 7)) * 8));
      }
      #pragma unroll
      for (int mt = 0; mt < 4; mt++)
        #pragma unroll
        for (int nt = 0; nt < 4; nt++)
          acc[mt][nt] = __builtin_amdgcn_mfma_f32_16x16x32_f16(a[mt], b[nt], acc[mt][nt], 0, 0, 0);
    }
  }
}

// ------------- QKV GEMM + table-RoPE + Q prescale -------------
__global__ __launch_bounds__(256) void qkv_gemm_kernel(
    const f16* __restrict__ xn, const f16* __restrict__ wt,
    const float* __restrict__ ctab, const float* __restrict__ stab,
    f16* __restrict__ qbuf, f16* __restrict__ kbuf, f16* __restrict__ vt) {
  __shared__ __align__(16) f16 As[128*64], Bs[128*64];
  int m0 = blockIdx.x * 128, n0 = blockIdx.y * 128;
  f32x4 acc[4][4] = {};
  gemm128_acc(xn, wt, m0, n0, As, Bs, acc);

  const int tid = threadIdx.x;
  const int wave = tid >> 6, lane = tid & 63;
  const int l16 = lane & 15, quad = lane >> 4;
  int ncol = n0 + (wave >> 1) * 64;      // head-aligned
  int which = ncol >> 9;                 // 0=q 1=k 2=v (wave-uniform)
  int head = (ncol >> 6) & 7;
  int mbase = m0 + (wave & 1) * 64;

  if (which <= 1) {                      // fused RoPE from tables
    #pragma unroll
    for (int mt = 0; mt < 4; mt++)
      #pragma unroll
      for (int nt = 0; nt < 2; nt++) {
        int d = nt*16 + l16;
        #pragma unroll
        for (int r = 0; r < 4; r++) {
          int t = (mbase + mt*16 + quad*4 + r) & 4095;
          float cv = ctab[t*32 + d], sv = stab[t*32 + d];
          float x1 = acc[mt][nt][r], x2 = acc[mt][nt+2][r];
          acc[mt][nt][r]   = x1*cv - x2*sv;
          acc[mt][nt+2][r] = x1*sv + x2*cv;
        }
      }
  }
  if (which < 2) {
    float osc = (which == 0) ? QSCALE : 1.0f;
    f16* dst = which ? kbuf : qbuf;
    #pragma unroll
    for (int mt = 0; mt < 4; mt++)
      #pragma unroll
      for (int nt = 0; nt < 4; nt++)
        #pragma unroll
        for (int r = 0; r < 4; r++) {
          int m = mbase + mt*16 + quad*4 + r;
          int b = m >> 12, t = m & 4095;
          dst[(((size_t)(b*NH + head))*S_LEN + t)*DH + nt*16 + l16] = (f16)(acc[mt][nt][r]*osc);
        }
  } else {                               // V transposed, pack 4 consecutive tokens
    #pragma unroll
    for (int mt = 0; mt < 4; mt++)
      #pragma unroll
      for (int nt = 0; nt < 4; nt++) {
        int m = mbase + mt*16 + quad*4;
        int b = m >> 12, t = m & 4095;
        int d = nt*16 + l16;
        f16x4 v4 = {(f16)acc[mt][nt][0], (f16)acc[mt][nt][1],
                    (f16)acc[mt][nt][2], (f16)acc[mt][nt][3]};
        *(f16x4*)(vt + ((size_t)((b*NH + head)*DH + d))*S_LEN + t) = v4;
      }
  }
}

// ------------- Flash attention (causal), 128 q-rows/block, swizzled single-buffer KV -------------
__global__ __launch_bounds__(256) void attn_kernel(
    const f16* __restrict__ qbuf, const f16* __restrict__ kbuf,
    const f16* __restrict__ vtb, f16* __restrict__ ao) {
  int bx = blockIdx.x;                   // 0..511; pair bx,bx+256 sums to const work
  int qtb = (bx < 256) ? (31 - (bx >> 4)) : ((bx - 256) >> 4);
  int bh = bx & 15;
  int tid = threadIdx.x;
  int wave = tid >> 6, lane = tid & 63;
  int l16 = lane & 15, quad = lane >> 4;

  const f16* Q = qbuf + (size_t)bh*S_LEN*DH;
  const f16* K = kbuf + (size_t)bh*S_LEN*DH;
  const f16* V = vtb  + (size_t)bh*DH*S_LEN;   // [dh][s]

  int rw = qtb*128 + wave*32;

  f16x8 qa[2][2];
  #pragma unroll
  for (int mf = 0; mf < 2; mf++) {
    const f16* qrow = Q + (size_t)(rw + mf*16 + l16)*DH + quad*8;
    qa[mf][0] = *(const f16x8*)(qrow);
    qa[mf][1] = *(const f16x8*)(qrow + 32);
  }

  f32x4 o[2][4] = {};
  float m_i[2][4], l_i[2][4];
  #pragma unroll
  for (int mf = 0; mf < 2; mf++)
    #pragma unroll
    for (int r = 0; r < 4; r++) { m_i[mf][r] = -1e30f; l_i[mf][r] = 0.f; }

  // XOR-swizzled 16B-chunk layout: [row][chunk c] stores logical chunk c^(row&7)
  __shared__ __align__(16) f16 kt[64*64];      // [kv][dh]
  __shared__ __align__(16) f16 vs[64*64];      // [dh][kv]
  __shared__ __align__(16) f16 pls[4*16*64];   // per-wave P staging [16][dh-chunks]

  int ntiles = 2*qtb + 2;
  int srow = tid >> 3, sc = tid & 7;
  int sw = ((sc ^ (srow & 7)) * 8);            // swizzled chunk byte... (f16 units)

  // prologue: stage tile 0
  {
    *(f16x8*)(kt + srow*64 + sw)      = *(const f16x8*)(K + (size_t)srow*DH + sc*8);
    *(f16x8*)(kt + (srow+32)*64 + sw) = *(const f16x8*)(K + (size_t)(srow+32)*DH + sc*8);
    *(f16x8*)(vs + srow*64 + sw)      = *(const f16x8*)(V + (size_t)srow*S_LEN + sc*8);
    *(f16x8*)(vs + (srow+32)*64 + sw) = *(const f16x8*)(V + (size_t)(srow+32)*S_LEN + sc*8);
  }
  __syncthreads();

  for (int it = 0; it < ntiles; ++it) {
    int kv0 = it * 64;
    bool have_next = (it + 1 < ntiles);
    f16x8 pk0, pk1, pv0, pv1;
    if (have_next) {
      int kvn = kv0 + 64;
      pk0 = *(const f16x8*)(K + (size_t)(kvn + srow)*DH + sc*8);
      pk1 = *(const f16x8*)(K + (size_t)(kvn + srow + 32)*DH + sc*8);
      pv0 = *(const f16x8*)(V + (size_t)srow*S_LEN + kvn + sc*8);
      pv1 = *(const f16x8*)(V + (size_t)(srow+32)*S_LEN + kvn + sc*8);
    }

    if (kv0 <= rw + 31) {
      // S = Q K^T
      f32x4 s[2][4];
      #pragma unroll
      for (int nt = 0; nt < 4; nt++) {
        int row = nt*16 + l16;
        f16x8 kf0 = *(const f16x8*)(kt + row*64 + ((quad ^ (l16 & 7)) * 8));
        f16x8 kf1 = *(const f16x8*)(kt + row*64 + (((quad + 4) ^ (l16 & 7)) * 8));
        f32x4 z0 = {}, z1 = {};
        z0 = __builtin_amdgcn_mfma_f32_16x16x32_f16(qa[0][0], kf0, z0, 0, 0, 0);
        z1 = __builtin_amdgcn_mfma_f32_16x16x32_f16(qa[1][0], kf0, z1, 0, 0, 0);
        s[0][nt] = __builtin_amdgcn_mfma_f32_16x16x32_f16(qa[0][1], kf1, z0, 0, 0, 0);
        s[1][nt] = __builtin_amdgcn_mfma_f32_16x16x32_f16(qa[1][1], kf1, z1, 0, 0, 0);
      }
      #pragma unroll
      for (int mf = 0; mf < 2; mf++) {
        int qbase = rw + mf*16;
        float rmax[4];
        #pragma unroll
        for (int r = 0; r < 4; r++) rmax[r] = -1e30f;
        if (kv0 + 63 > qbase) {          // diagonal tile: mask
          #pragma unroll
          for (int nt = 0; nt < 4; nt++) {
            int key = kv0 + nt*16 + l16;
            #pragma unroll
            for (int r = 0; r < 4; r++) {
              float v = s[mf][nt][r];
              if (key > qbase + quad*4 + r) v = -1e30f;
              s[mf][nt][r] = v;
              rmax[r] = fmaxf(rmax[r], v);
            }
          }
        } else {
          #pragma unroll
          for (int nt = 0; nt < 4; nt++)
            #pragma unroll
            for (int r = 0; r < 4; r++) rmax[r] = fmaxf(rmax[r], s[mf][nt][r]);
        }
        #pragma unroll
        for (int r = 0; r < 4; r++) {
          float v = rmax[r];
          v = fmaxf(v, __shfl_xor(v, 1));
          v = fmaxf(v, __shfl_xor(v, 2));
          v = fmaxf(v, __shfl_xor(v, 4));
          v = fmaxf(v, __shfl_xor(v, 8));
          rmax[r] = v;
        }
        float alpha[4], rsum[4];
        #pragma unroll
        for (int r = 0; r < 4; r++) {
          float mnew = fmaxf(m_i[mf][r], rmax[r]);
          alpha[r] = exp2f(m_i[mf][r] - mnew);
          m_i[mf][r] = mnew;
          rsum[r] = 0.f;
        }
        #pragma unroll
        for (int nt = 0; nt < 4; nt++)
          #pragma unroll
          for (int r = 0; r < 4; r++) {
            float p = exp2f(s[mf][nt][r] - m_i[mf][r]);
            s[mf][nt][r] = p;
            rsum[r] += p;
          }
        #pragma unroll
        for (int r = 0; r < 4; r++) {
          float v = rsum[r];
          v += __shfl_xor(v, 1);
          v += __shfl_xor(v, 2);
          v += __shfl_xor(v, 4);
          v += __shfl_xor(v, 8);
          l_i[mf][r] = l_i[mf][r]*alpha[r] + v;
        }
        // P (C-layout) -> swizzled LDS -> A-layout; rescale O
        #pragma unroll
        for (int nt = 0; nt < 4; nt++)
          #pragma unroll
          for (int r = 0; r < 4; r++) {
            int prow = quad*4 + r;
            int c = nt*2 + (l16 >> 3);
            pls[wave*1024 + prow*64 + ((c ^ (prow & 7)) * 8) + (l16 & 7)] = (f16)s[mf][nt][r];
            o[mf][nt][r] *= alpha[r];
          }
        f16x8 pa0 = *(const f16x8*)(pls + wave*1024 + l16*64 + ((quad ^ (l16 & 7)) * 8));
        f16x8 pa1 = *(const f16x8*)(pls + wave*1024 + l16*64 + (((quad + 4) ^ (l16 & 7)) * 8));
        #pragma unroll
        for (int nt = 0; nt < 4; nt++) {
          int row = nt*16 + l16;
          f16x8 vf0 = *(const f16x8*)(vs + row*64 + ((quad ^ (l16 & 7)) * 8));
          f16x8 vf1 = *(const f16x8*)(vs + row*64 + (((quad + 4) ^ (l16 & 7)) * 8));
          o[mf][nt] = __builtin_amdgcn_mfma_f32_16x16x32_f16(pa0, vf0, o[mf][nt], 0, 0, 0);
          o[mf][nt] = __builtin_amdgcn_mfma_f32_16x16x32_f16(pa1, vf1, o[mf][nt], 0, 0, 0);
        }
      }
    }

    __syncthreads();                     // all reads of current tile done
    if (have_next) {
      *(f16x8*)(kt + srow*64 + sw)      = pk0;
      *(f16x8*)(kt + (srow+32)*64 + sw) = pk1;
      *(f16x8*)(vs + srow*64 + sw)      = pv0;
      *(f16x8*)(vs + (srow+32)*64 + sw) = pv1;
    }
    __syncthreads();                     // writes visible
  }

  int b = bh >> 3, h = bh & 7;
  #pragma unroll
  for (int mf = 0; mf < 2; mf++)
    #pragma unroll
    for (int r = 0; r < 4; r++) {
      float invl = 1.0f / l_i[mf][r];
      int t = rw + mf*16 + quad*4 + r;
      size_t rowoff = ((size_t)(b*S_LEN + t))*DIM + h*DH;
      #pragma unroll
      for (int nt = 0; nt < 4; nt++)
        ao[rowoff + nt*16 + l16] = (f16)(o[mf][nt][r]*invl);
    }
}

// ------------- Output GEMM: ao[8192,512] @ Wo -> out f32 -------------
__global__ __launch_bounds__(256) void out_gemm_kernel(
    const f16* __restrict__ ao, const f16* __restrict__ wot,
    float* __restrict__ out) {
  __shared__ __align__(16) f16 As[128*64], Bs[128*64];
  int m0 = blockIdx.x * 128, n0 = blockIdx.y * 128;
  f32x4 acc[4][4] = {};
  gemm128_acc(ao, wot, m0, n0, As, Bs, acc);

  const int tid = threadIdx.x;
  const int wave = tid >> 6, lane = tid & 63;
  const int l16 = lane & 15, quad = lane >> 4;
  int ncol = n0 + (wave >> 1) * 64;
  int mbase = m0 + (wave & 1) * 64;
  #pragma unroll
  for (int mt = 0; mt < 4; mt++)
    #pragma unroll
    for (int nt = 0; nt < 4; nt++)
      #pragma unroll
      for (int r = 0; r < 4; r++)
        out[(size_t)(mbase + mt*16 + quad*4 + r)*DIM + ncol + nt*16 + l16] = acc[mt][nt][r];
}

extern "C" void kernel_launch(void* const* d_in, const int* in_sizes, int n_in,
                              void* d_out, int out_size, void* d_ws, size_t ws_size,
                              hipStream_t stream) {
  const float* x     = (const float*)d_in[0];
  const float* scale = (const float*)d_in[1];
  const float* Wq    = (const float*)d_in[2];
  const float* Wk    = (const float*)d_in[3];
  const float* Wv    = (const float*)d_in[4];
  const float* Wo    = (const float*)d_in[5];
  float* out = (float*)d_out;

  const size_t ROWS = (size_t)BATCH * S_LEN;   // 8192
  char* ws = (char*)d_ws;
  f16* xn     = (f16*)ws;  ws += ROWS * DIM * sizeof(f16);            // 8 MB (reused as ao)
  f16* wt_qkv = (f16*)ws;  ws += (size_t)3 * DIM * DIM * sizeof(f16); // 1.5 MB
  f16* wo_t   = (f16*)ws;  ws += (size_t)DIM * DIM * sizeof(f16);     // 0.5 MB
  f16* qb     = (f16*)ws;  ws += (size_t)BHDIM * S_LEN * DH * sizeof(f16); // 8 MB
  f16* kb     = (f16*)ws;  ws += (size_t)BHDIM * S_LEN * DH * sizeof(f16); // 8 MB
  f16* vt     = (f16*)ws;  ws += (size_t)BHDIM * S_LEN * DH * sizeof(f16); // 8 MB
  float* ctab = (float*)ws; ws += (size_t)S_LEN * 32 * sizeof(float);  // 0.5 MB
  float* stab = (float*)ws; ws += (size_t)S_LEN * 32 * sizeof(float);  // 0.5 MB
  f16* ao     = xn;  // overlay: xn dead after qkv_gemm

  size_t need = (size_t)(ws - (char*)d_ws);
  if (ws_size < need) return;

  rmsnorm_kernel   <<<ROWS, 256, 0, stream>>>(x, scale, xn);
  transpose_kernel <<<dim3(16,16,4), dim3(32,8), 0, stream>>>(Wq, Wk, Wv, Wo, wt_qkv, wo_t);
  rope_table_kernel<<<512, 256, 0, stream>>>(ctab, stab);
  qkv_gemm_kernel  <<<dim3(64,12), 256, 0, stream>>>(xn, wt_qkv, ctab, stab, qb, kb, vt);
  attn_kernel      <<<512, 256, 0, stream>>>(qb, kb, vt, ao);
  out_gemm_kernel  <<<dim3(64,4), 256, 0, stream>>>(ao, wo_t, out);
}

// Round 8
// 234.523 us; speedup vs baseline: 2.9224x; 1.2931x over previous
//
#include <hip/hip_runtime.h>
#include <hip/hip_bf16.h>

typedef _Float16 f16;
typedef _Float16 f16x4 __attribute__((ext_vector_type(4)));
typedef _Float16 f16x8 __attribute__((ext_vector_type(8)));
typedef float f32x4 __attribute__((ext_vector_type(4)));

#define S_LEN 4096
#define DIM   512
#define NH    8
#define DH    64
#define BATCH 2
#define BHDIM (BATCH*NH)   // 16

// Q pre-scale: 1/sqrt(64) * log2(e)  (softmax done in exp2 domain)
#define QSCALE 0.18033688011112042f

__device__ __forceinline__ void gld16(const f16* g, f16* l) {
#if __has_builtin(__builtin_amdgcn_global_load_lds)
  __builtin_amdgcn_global_load_lds((const __attribute__((address_space(1))) void*)g,
                                   (__attribute__((address_space(3))) void*)l, 16, 0, 0);
#else
  *(f16x8*)l = *(const f16x8*)g;
#endif
}

// ---------------- RMSNorm: x[8192,512] f32 -> xn f16 ----------------
__global__ __launch_bounds__(256) void rmsnorm_kernel(
    const float* __restrict__ x, const float* __restrict__ scale,
    f16* __restrict__ xn) {
  int row = blockIdx.x;
  int tid = threadIdx.x;
  const float* xr = x + (size_t)row * DIM;
  float2 v = *(const float2*)(xr + tid*2);
  float ss = v.x*v.x + v.y*v.y;
  #pragma unroll
  for (int off = 32; off > 0; off >>= 1) ss += __shfl_down(ss, off);
  __shared__ float red[4];
  if ((tid & 63) == 0) red[tid >> 6] = ss;
  __syncthreads();
  float tot = red[0] + red[1] + red[2] + red[3];
  float inv = rsqrtf(tot * (1.0f/DIM) + 1e-6f);
  float2 s = *(const float2*)(scale + tid*2);
  xn[(size_t)row*DIM + tid*2+0] = (f16)(v.x*inv*s.x);
  xn[(size_t)row*DIM + tid*2+1] = (f16)(v.y*inv*s.y);
}

// ------------- Transpose+convert weights: W[k][n] f32 -> Wt[n][k] f16 -------------
__global__ void transpose_kernel(const float* __restrict__ Wq,
                                 const float* __restrict__ Wk,
                                 const float* __restrict__ Wv,
                                 const float* __restrict__ Wo,
                                 f16* __restrict__ wt_qkv, f16* __restrict__ wo_t) {
  __shared__ f16 tile[32][33];
  int mat = blockIdx.z;
  const float* src = (mat == 0) ? Wq : (mat == 1) ? Wk : (mat == 2) ? Wv : Wo;
  f16* dst = (mat < 3) ? (wt_qkv + (size_t)mat*DIM*DIM) : wo_t;
  int k0 = blockIdx.y * 32, n0 = blockIdx.x * 32;
  int tx = threadIdx.x, ty = threadIdx.y;  // (32, 8)
  #pragma unroll
  for (int i = 0; i < 32; i += 8)
    tile[ty+i][tx] = (f16)src[(size_t)(k0+ty+i)*DIM + n0+tx];
  __syncthreads();
  #pragma unroll
  for (int i = 0; i < 32; i += 8)
    dst[(size_t)(n0+ty+i)*DIM + k0+tx] = tile[tx][ty+i];
}

// ------------- RoPE cos/sin tables: [4096][32] f32 -------------
__global__ __launch_bounds__(256) void rope_table_kernel(float* __restrict__ ctab,
                                                         float* __restrict__ stab) {
  int idx = blockIdx.x*256 + threadIdx.x;   // 0..131071
  int t = idx >> 5, d = idx & 31;
  float theta = exp2f(-(float)d * (19.931568569324174f / 32.0f));
  float sv, cv;
  sincosf((float)t * theta, &sv, &cv);
  ctab[idx] = cv; stab[idx] = sv;
}

// ------------- m97-style 128x128 GEMM core: C = A[M,512] * Bt[N,512]^T -------------
__device__ __forceinline__ void gemm128_acc(
    const f16* __restrict__ A, const f16* __restrict__ Bt,
    int m0, int n0, f16* As, f16* Bs, f32x4 (&acc)[4][4]) {
  const int tid = threadIdx.x;
  const int wave = tid >> 6, lane = tid & 63;
  const int l16 = lane & 15, quad = lane >> 4;
  const int mrow = (wave & 1) * 64, ncol = (wave >> 1) * 64;
  const int srow = tid >> 3;                    // 0..31
  const int gc = (tid & 7) ^ ((tid >> 3) & 7);  // swizzled source chunk

  for (int k0 = 0; k0 < DIM; k0 += 64) {
    if (k0) __syncthreads();
    #pragma unroll
    for (int i = 0; i < 4; i++) {
      gld16(A  + (size_t)(m0 + i*32 + srow)*DIM + k0 + gc*8, As + i*2048 + tid*8);
      gld16(Bt + (size_t)(n0 + i*32 + srow)*DIM + k0 + gc*8, Bs + i*2048 + tid*8);
    }
    __syncthreads();
    #pragma unroll
    for (int kc = 0; kc < 2; kc++) {
      f16x8 a[4], b[4];
      #pragma unroll
      for (int mt = 0; mt < 4; mt++) {
        int row = mrow + mt*16 + l16;
        a[mt] = *(const f16x8*)(As + row*64 + (((quad + 4*kc) ^ (l16 & 7)) * 8));
      }
      #pragma unroll
      for (int nt = 0; nt < 4; nt++) {
        int row = ncol + nt*16 + l16;
        b[nt] = *(const f16x8*)(Bs + row*64 + (((quad + 4*kc) ^ (l16 & 7)) * 8));
      }
      #pragma unroll
      for (int mt = 0; mt < 4; mt++)
        #pragma unroll
        for (int nt = 0; nt < 4; nt++)
          acc[mt][nt] = __builtin_amdgcn_mfma_f32_16x16x32_f16(a[mt], b[nt], acc[mt][nt], 0, 0, 0);
    }
  }
}

// ------------- QKV GEMM + table-RoPE + Q prescale -------------
__global__ __launch_bounds__(256) void qkv_gemm_kernel(
    const f16* __restrict__ xn, const f16* __restrict__ wt,
    const float* __restrict__ ctab, const float* __restrict__ stab,
    f16* __restrict__ qbuf, f16* __restrict__ kbuf, f16* __restrict__ vt) {
  __shared__ __align__(16) f16 As[128*64], Bs[128*64];
  int m0 = blockIdx.x * 128, n0 = blockIdx.y * 128;
  f32x4 acc[4][4] = {};
  gemm128_acc(xn, wt, m0, n0, As, Bs, acc);

  const int tid = threadIdx.x;
  const int wave = tid >> 6, lane = tid & 63;
  const int l16 = lane & 15, quad = lane >> 4;
  int ncol = n0 + (wave >> 1) * 64;      // head-aligned
  int which = ncol >> 9;                 // 0=q 1=k 2=v (wave-uniform)
  int head = (ncol >> 6) & 7;
  int mbase = m0 + (wave & 1) * 64;

  if (which <= 1) {                      // fused RoPE from tables
    #pragma unroll
    for (int mt = 0; mt < 4; mt++)
      #pragma unroll
      for (int nt = 0; nt < 2; nt++) {
        int d = nt*16 + l16;
        #pragma unroll
        for (int r = 0; r < 4; r++) {
          int t = (mbase + mt*16 + quad*4 + r) & 4095;
          float cv = ctab[t*32 + d], sv = stab[t*32 + d];
          float x1 = acc[mt][nt][r], x2 = acc[mt][nt+2][r];
          acc[mt][nt][r]   = x1*cv - x2*sv;
          acc[mt][nt+2][r] = x1*sv + x2*cv;
        }
      }
  }
  if (which < 2) {
    float osc = (which == 0) ? QSCALE : 1.0f;
    f16* dst = which ? kbuf : qbuf;
    #pragma unroll
    for (int mt = 0; mt < 4; mt++)
      #pragma unroll
      for (int nt = 0; nt < 4; nt++)
        #pragma unroll
        for (int r = 0; r < 4; r++) {
          int m = mbase + mt*16 + quad*4 + r;
          int b = m >> 12, t = m & 4095;
          dst[(((size_t)(b*NH + head))*S_LEN + t)*DH + nt*16 + l16] = (f16)(acc[mt][nt][r]*osc);
        }
  } else {                               // V transposed, pack 4 consecutive tokens
    #pragma unroll
    for (int mt = 0; mt < 4; mt++)
      #pragma unroll
      for (int nt = 0; nt < 4; nt++) {
        int m = mbase + mt*16 + quad*4;
        int b = m >> 12, t = m & 4095;
        int d = nt*16 + l16;
        f16x4 v4 = {(f16)acc[mt][nt][0], (f16)acc[mt][nt][1],
                    (f16)acc[mt][nt][2], (f16)acc[mt][nt][3]};
        *(f16x4*)(vt + ((size_t)((b*NH + head)*DH + d))*S_LEN + t) = v4;
      }
  }
}

// ------------- Flash attention (causal), 128 q-rows/block, 128-key tiles, S^T softmax -------------
__global__ __launch_bounds__(256, 2) void attn_kernel(
    const f16* __restrict__ qbuf, const f16* __restrict__ kbuf,
    const f16* __restrict__ vtb, f16* __restrict__ ao) {
  int bx = blockIdx.x;                   // 0..511; pair bx,bx+256 sums to const work
  int qtb = (bx < 256) ? (31 - (bx >> 4)) : ((bx - 256) >> 4);
  int bh = bx & 15;
  int tid = threadIdx.x;
  int wave = tid >> 6, lane = tid & 63;
  int l16 = lane & 15, quad = lane >> 4;

  const f16* Q = qbuf + (size_t)bh*S_LEN*DH;
  const f16* K = kbuf + (size_t)bh*S_LEN*DH;
  const f16* V = vtb  + (size_t)bh*DH*S_LEN;   // [dh][s]

  int rw = qtb*128 + wave*32;

  // Q fragments (identical register content serves as A- or B-operand)
  f16x8 qa[2][2];
  #pragma unroll
  for (int mf = 0; mf < 2; mf++) {
    const f16* qrow = Q + (size_t)(rw + mf*16 + l16)*DH + quad*8;
    qa[mf][0] = *(const f16x8*)(qrow);
    qa[mf][1] = *(const f16x8*)(qrow + 32);
  }

  f32x4 o[2][4] = {};                    // O C-layout [qrow=quad*4+r][dh=dnt*16+l16]
  float m_i[2] = {-1e30f, -1e30f};       // per-lane state for qrow = l16 (replicated over quads)
  float l_i[2] = {0.f, 0.f};

  // XOR-swizzled 16B-chunk LDS
  __shared__ __align__(16) f16 kt[128*64];     // [kv 128][dh 64]
  __shared__ __align__(16) f16 vs[64*128];     // [dh 64][kv 128]
  __shared__ __align__(16) f16 pls[4*16*128];  // per-wave P [qrow 16][key 128]

  int ntiles = qtb + 1;

  // staging maps (4x 16B chunks per thread per tile)
  int krow = tid >> 1, kc0 = (tid & 1) * 4;
  int vrow = tid >> 2, vc0 = (tid & 3) * 4;

  // prologue: stage tile 0
  #pragma unroll
  for (int i = 0; i < 4; i++) {
    *(f16x8*)(kt + krow*64  + (((kc0+i) ^ (krow & 7))*8)) = *(const f16x8*)(K + (size_t)krow*DH + (kc0+i)*8);
    *(f16x8*)(vs + vrow*128 + (((vc0+i) ^ (vrow & 7))*8)) = *(const f16x8*)(V + (size_t)vrow*S_LEN + (vc0+i)*8);
  }
  __syncthreads();

  for (int it = 0; it < ntiles; ++it) {
    int kv0 = it * 128;
    bool have_next = (it + 1 < ntiles);
    f16x8 pk[4], pv[4];
    if (have_next) {
      int kvn = kv0 + 128;
      #pragma unroll
      for (int i = 0; i < 4; i++) {
        pk[i] = *(const f16x8*)(K + (size_t)(kvn + krow)*DH + (kc0+i)*8);
        pv[i] = *(const f16x8*)(V + (size_t)vrow*S_LEN + kvn + (vc0+i)*8);
      }
    }

    // ---- S^T = K Q^T : st[mf][nt], C-layout row=key_local quad*4+r, col=qrow_local l16 ----
    f32x4 st[2][8];
    #pragma unroll
    for (int nt = 0; nt < 8; nt++) {
      int row = nt*16 + l16;
      f16x8 kf0 = *(const f16x8*)(kt + row*64 + (((quad)     ^ (row & 7))*8));
      f16x8 kf1 = *(const f16x8*)(kt + row*64 + (((quad + 4) ^ (row & 7))*8));
      f32x4 z0 = {}, z1 = {};
      z0 = __builtin_amdgcn_mfma_f32_16x16x32_f16(kf0, qa[0][0], z0, 0, 0, 0);
      z1 = __builtin_amdgcn_mfma_f32_16x16x32_f16(kf0, qa[1][0], z1, 0, 0, 0);
      st[0][nt] = __builtin_amdgcn_mfma_f32_16x16x32_f16(kf1, qa[0][1], z0, 0, 0, 0);
      st[1][nt] = __builtin_amdgcn_mfma_f32_16x16x32_f16(kf1, qa[1][1], z1, 0, 0, 0);
    }

    bool last = (it == ntiles - 1);
    #pragma unroll
    for (int mf = 0; mf < 2; mf++) {
      int qrow = rw + mf*16 + l16;
      float rmx = -1e30f;
      if (last) {                        // diagonal tile: causal mask
        #pragma unroll
        for (int nt = 0; nt < 8; nt++) {
          int kbase = kv0 + nt*16 + quad*4;
          #pragma unroll
          for (int r = 0; r < 4; r++) {
            float v = st[mf][nt][r];
            if (kbase + r > qrow) v = -1e30f;
            st[mf][nt][r] = v;
            rmx = fmaxf(rmx, v);
          }
        }
      } else {
        #pragma unroll
        for (int nt = 0; nt < 8; nt++)
          #pragma unroll
          for (int r = 0; r < 4; r++) rmx = fmaxf(rmx, st[mf][nt][r]);
      }
      rmx = fmaxf(rmx, __shfl_xor(rmx, 16));
      rmx = fmaxf(rmx, __shfl_xor(rmx, 32));
      float mnew = fmaxf(m_i[mf], rmx);
      float alpha = exp2f(m_i[mf] - mnew);
      m_i[mf] = mnew;
      // alpha to O-row layout (qrow_local = quad*4+r lives in lane l16=quad*4+r)
      float al[4];
      #pragma unroll
      for (int r = 0; r < 4; r++) al[r] = __shfl(alpha, quad*4 + r);
      #pragma unroll
      for (int dnt = 0; dnt < 4; dnt++)
        #pragma unroll
        for (int r = 0; r < 4; r++) o[mf][dnt][r] *= al[r];
      // P = exp2(st - mnew), pack f16x4 per nt, store to pls[qrow_local][key]
      float rs = 0.f;
      f16* plw = pls + wave*2048 + l16*128;
      #pragma unroll
      for (int nt = 0; nt < 8; nt++) {
        f16x4 p4;
        #pragma unroll
        for (int r = 0; r < 4; r++) {
          float p = exp2f(st[mf][nt][r] - mnew);
          rs += p;
          p4[r] = (f16)p;
        }
        int cw = nt*2 + (quad >> 1);
        *(f16x4*)(plw + ((cw ^ (l16 & 7))*8) + (quad & 1)*4) = p4;
      }
      rs += __shfl_xor(rs, 16);
      rs += __shfl_xor(rs, 32);
      l_i[mf] = l_i[mf]*alpha + rs;
      // read P as A-frags, PV
      f16x8 pa[4];
      #pragma unroll
      for (int kc = 0; kc < 4; kc++)
        pa[kc] = *(const f16x8*)(plw + (((kc*4 + quad) ^ (l16 & 7))*8));
      #pragma unroll
      for (int dnt = 0; dnt < 4; dnt++) {
        int vrow2 = dnt*16 + l16;
        #pragma unroll
        for (int kc = 0; kc < 4; kc++) {
          f16x8 vf = *(const f16x8*)(vs + vrow2*128 + (((kc*4 + quad) ^ (vrow2 & 7))*8));
          o[mf][dnt] = __builtin_amdgcn_mfma_f32_16x16x32_f16(pa[kc], vf, o[mf][dnt], 0, 0, 0);
        }
      }
    }

    __syncthreads();                     // readers done with current tile
    if (have_next) {
      #pragma unroll
      for (int i = 0; i < 4; i++) {
        *(f16x8*)(kt + krow*64  + (((kc0+i) ^ (krow & 7))*8)) = pk[i];
        *(f16x8*)(vs + vrow*128 + (((vc0+i) ^ (vrow & 7))*8)) = pv[i];
      }
    }
    __syncthreads();                     // writes visible
  }

  // epilogue
  int b = bh >> 3, h = bh & 7;
  #pragma unroll
  for (int mf = 0; mf < 2; mf++) {
    float lr[4];
    #pragma unroll
    for (int r = 0; r < 4; r++) lr[r] = __shfl(l_i[mf], quad*4 + r);
    #pragma unroll
    for (int r = 0; r < 4; r++) {
      float invl = 1.0f / lr[r];
      int t = rw + mf*16 + quad*4 + r;
      size_t rowoff = ((size_t)(b*S_LEN + t))*DIM + h*DH;
      #pragma unroll
      for (int dnt = 0; dnt < 4; dnt++)
        ao[rowoff + dnt*16 + l16] = (f16)(o[mf][dnt][r]*invl);
    }
  }
}

// ------------- Output GEMM: ao[8192,512] @ Wo -> out f32 -------------
__global__ __launch_bounds__(256) void out_gemm_kernel(
    const f16* __restrict__ ao, const f16* __restrict__ wot,
    float* __restrict__ out) {
  __shared__ __align__(16) f16 As[128*64], Bs[128*64];
  int m0 = blockIdx.x * 128, n0 = blockIdx.y * 128;
  f32x4 acc[4][4] = {};
  gemm128_acc(ao, wot, m0, n0, As, Bs, acc);

  const int tid = threadIdx.x;
  const int wave = tid >> 6, lane = tid & 63;
  const int l16 = lane & 15, quad = lane >> 4;
  int ncol = n0 + (wave >> 1) * 64;
  int mbase = m0 + (wave & 1) * 64;
  #pragma unroll
  for (int mt = 0; mt < 4; mt++)
    #pragma unroll
    for (int nt = 0; nt < 4; nt++)
      #pragma unroll
      for (int r = 0; r < 4; r++)
        out[(size_t)(mbase + mt*16 + quad*4 + r)*DIM + ncol + nt*16 + l16] = acc[mt][nt][r];
}

extern "C" void kernel_launch(void* const* d_in, const int* in_sizes, int n_in,
                              void* d_out, int out_size, void* d_ws, size_t ws_size,
                              hipStream_t stream) {
  const float* x     = (const float*)d_in[0];
  const float* scale = (const float*)d_in[1];
  const float* Wq    = (const float*)d_in[2];
  const float* Wk    = (const float*)d_in[3];
  const float* Wv    = (const float*)d_in[4];
  const float* Wo    = (const float*)d_in[5];
  float* out = (float*)d_out;

  const size_t ROWS = (size_t)BATCH * S_LEN;   // 8192
  char* ws = (char*)d_ws;
  f16* xn     = (f16*)ws;  ws += ROWS * DIM * sizeof(f16);            // 8 MB (reused as ao)
  f16* wt_qkv = (f16*)ws;  ws += (size_t)3 * DIM * DIM * sizeof(f16); // 1.5 MB
  f16* wo_t   = (f16*)ws;  ws += (size_t)DIM * DIM * sizeof(f16);     // 0.5 MB
  f16* qb     = (f16*)ws;  ws += (size_t)BHDIM * S_LEN * DH * sizeof(f16); // 8 MB
  f16* kb     = (f16*)ws;  ws += (size_t)BHDIM * S_LEN * DH * sizeof(f16); // 8 MB
  f16* vt     = (f16*)ws;  ws += (size_t)BHDIM * S_LEN * DH * sizeof(f16); // 8 MB
  float* ctab = (float*)ws; ws += (size_t)S_LEN * 32 * sizeof(float);  // 0.5 MB
  float* stab = (float*)ws; ws += (size_t)S_LEN * 32 * sizeof(float);  // 0.5 MB
  f16* ao     = xn;  // overlay: xn dead after qkv_gemm

  size_t need = (size_t)(ws - (char*)d_ws);
  if (ws_size < need) return;

  rmsnorm_kernel   <<<ROWS, 256, 0, stream>>>(x, scale, xn);
  transpose_kernel <<<dim3(16,16,4), dim3(32,8), 0, stream>>>(Wq, Wk, Wv, Wo, wt_qkv, wo_t);
  rope_table_kernel<<<512, 256, 0, stream>>>(ctab, stab);
  qkv_gemm_kernel  <<<dim3(64,12), 256, 0, stream>>>(xn, wt_qkv, ctab, stab, qb, kb, vt);
  attn_kernel      <<<512, 256, 0, stream>>>(qb, kb, vt, ao);
  out_gemm_kernel  <<<dim3(64,4), 256, 0, stream>>>(ao, wo_t, out);
}